// Round 6
// baseline (385.951 us; speedup 1.0000x reference)
//
#include <hip/hip_runtime.h>
#include <hip/hip_bf16.h>
#include <math.h>

#define BB 8
#define FH 8
#define NN 2048
#define TIN 5
#define H1 32
#define H2 64

typedef const void* cvp;
typedef __attribute__((ext_vector_type(8))) short short8;
typedef __attribute__((ext_vector_type(4))) float floatx4;

__device__ __forceinline__ float ldx(cvp p, int i, int bf) {
  if (bf) return __bfloat162float(((const __hip_bfloat16*)p)[i]);
  return ((const float*)p)[i];
}

__device__ __forceinline__ float4 ld4(cvp p, int i, int bf) {
  if (bf) {
    const __hip_bfloat162* q = (const __hip_bfloat162*)p;
    float2 a = __bfloat1622float2(q[(i >> 1)]);
    float2 b = __bfloat1622float2(q[(i >> 1) + 1]);
    return make_float4(a.x, a.y, b.x, b.y);
  }
  return ((const float4*)p)[i >> 2];
}

// Fast sigmoid/tanh: __expf + __fdividef. abs error ~1e-6 in h, far under the
// bf16-rounding-dominated output error (4.88e-4).
__device__ __forceinline__ float sigf(float x) {
  return __fdividef(1.f, 1.f + __expf(-x));
}
__device__ __forceinline__ float tanhfast(float x) {
  float e = __expf(x + x);
  return 1.f - __fdividef(2.f, e + 1.f);
}

// Inline bf16-vs-fp32 detector: 64 word samples of W_ih.
__device__ __forceinline__ int detect_bf(cvp wih) {
  unsigned word = ((const unsigned*)wih)[threadIdx.x & 63];
  unsigned e = (word >> 7) & 0xFFu;
  unsigned long long bal = __ballot(e >= 100u && e <= 150u);
  return __popcll(bal) > 44;
}

// ---------------------------------------------------------------- LSTM
// (unchanged from round 5 -- adj-BW bound; step-tail micro-opts proven
// neutral, structure kept)
__global__ __launch_bounds__(256, 2) void k_lstm(
    cvp hist, cvp W1, cvp b1, cvp W_ih, cvp W_hh, cvp b_ih, cvp b_hh,
    cvp Wg, cvp a_src, cvp a_dst, const int* __restrict__ adj,
    __hip_bfloat16* __restrict__ WhFr, float* __restrict__ sv,
    float* __restrict__ dv, unsigned* __restrict__ gmask) {
  __shared__ __align__(16) float xh[4][96];      // per node: x[0..31], h[32..95]
  __shared__ float gbuf[4][256];
  __shared__ float W1s[H1][41];                  // bank-padded
  __shared__ float b1s[H1];
  __shared__ float xstage[2][4][40];             // double-buffered
  __shared__ __align__(16) unsigned pmsk[2048];  // 32 rows x 64 words

  int bf = detect_bf(W_ih);
  int tid = threadIdx.x;
  int w = tid >> 6, lane = tid & 63;
  int g = tid;
  int n0 = blockIdx.x << 2;
  int node_w = n0 + w;

  // adj chunk: batch cb, rows ci..ci+31 (disjoint across blocks)
  int cb = blockIdx.x >> 6;
  int ci = (blockIdx.x & 63) << 5;
  const int4* adj4 = (const int4*)(adj + ((size_t)(cb * 2 + 1) * NN + ci) * NN);

  for (int i = tid; i < H1 * 40; i += 256) W1s[i / 40][i % 40] = ldx(W1, i, bf);
  if (tid < H1) b1s[tid] = ldx(b1, tid, bf);
  for (int i = tid; i < 2048; i += 256) pmsk[i] = 0u;
  // stage hist t=0 (prologue; S1 of t=0 orders it before h1)
  int snd = tid / 40, sr = tid % 40;
  int sti = sr >> 3, sf = sr & 7;
  if (tid < 160)
    xstage[0][snd][sr] = ldx(hist, ((0 * FH + sf) * NN + n0 + snd) * TIN + sti, bf);
  xh[w][32 + lane] = 0.f;

  float wreg[96];
#pragma unroll
  for (int kq = 0; kq < 8; ++kq) {
    float4 v = ld4(W_ih, g * 32 + (kq << 2), bf);
    wreg[(kq << 2) + 0] = v.x; wreg[(kq << 2) + 1] = v.y;
    wreg[(kq << 2) + 2] = v.z; wreg[(kq << 2) + 3] = v.w;
  }
#pragma unroll
  for (int kq = 0; kq < 16; ++kq) {
    float4 v = ld4(W_hh, g * 64 + (kq << 2), bf);
    wreg[32 + (kq << 2) + 0] = v.x; wreg[32 + (kq << 2) + 1] = v.y;
    wreg[32 + (kq << 2) + 2] = v.z; wreg[32 + (kq << 2) + 3] = v.w;
  }
  float bias = ldx(b_ih, g, bf) + ldx(b_hh, g, bf);

  float wgreg[64];
#pragma unroll
  for (int k = 0; k < H2; ++k) wgreg[k] = ldx(Wg, (k << 6) + lane, bf);
  float as = ldx(a_src, lane, bf);
  float ad = ldx(a_dst, lane, bf);

  // WhFr short8 fragment index for (node=node_w, col=lane); batch added per t.
  size_t o8base = ((size_t)(node_w >> 5) * 256) + ((size_t)(lane >> 4) * 64) +
                  (((node_w >> 3) & 3) * 16) + (lane & 15);
  int jj = node_w & 7;

  float c = 0.f;

  for (int t = 0; t < BB; ++t) {
    // issue hist(t+1) into a register (consumed by ds_write in the tail)
    float hv = 0.f;
    if (t < 7 && tid < 160)
      hv = ldx(hist, (((t + 1) * FH + sf) * NN + n0 + snd) * TIN + sti, bf);
    // issue adj batch A (consumed after the GEMM -> hidden)
    int4 av0[4];
#pragma unroll
    for (int u = 0; u < 4; ++u) av0[u] = adj4[(t << 11) + (u << 8) + tid];
    __syncthreads();  // S1: xstage[t&1] + xh h (prev tail) ready
    if (tid < 128) {  // h1 for t
      int nd = tid >> 5, k = tid & 31;
      float acc = b1s[k];
#pragma unroll
      for (int j = 0; j < 40; ++j) acc += W1s[k][j] * xstage[t & 1][nd][j];
      xh[nd][k] = (acc > 0.f) ? acc : expm1f(acc);
    }
    __syncthreads();  // S2: xh x-part ready
    float acc[4] = {bias, bias, bias, bias};
    const float4* xq0 = (const float4*)xh[0];
    const float4* xq1 = (const float4*)xh[1];
    const float4* xq2 = (const float4*)xh[2];
    const float4* xq3 = (const float4*)xh[3];
#pragma unroll
    for (int kq = 0; kq < 24; ++kq) {
      float w0 = wreg[(kq << 2) + 0], w1 = wreg[(kq << 2) + 1];
      float w2 = wreg[(kq << 2) + 2], w3 = wreg[(kq << 2) + 3];
      float4 v0 = xq0[kq], v1 = xq1[kq], v2 = xq2[kq], v3 = xq3[kq];
      acc[0] += w0 * v0.x + w1 * v0.y + w2 * v0.z + w3 * v0.w;
      acc[1] += w0 * v1.x + w1 * v1.y + w2 * v1.z + w3 * v1.w;
      acc[2] += w0 * v2.x + w1 * v2.y + w2 * v2.z + w3 * v2.w;
      acc[3] += w0 * v3.x + w1 * v3.y + w2 * v3.z + w3 * v3.w;
    }
#pragma unroll
    for (int nd = 0; nd < 4; ++nd) gbuf[nd][g] = acc[nd];
    // consume batch A, issue batch B
#pragma unroll
    for (int u = 0; u < 4; ++u) {
      int gg = (t << 11) + (u << 8) + tid;
      unsigned nib = (av0[u].x != 0 ? 1u : 0u) | (av0[u].y != 0 ? 2u : 0u) |
                     (av0[u].z != 0 ? 4u : 0u) | (av0[u].w != 0 ? 8u : 0u);
      atomicOr(&pmsk[((gg >> 9) << 6) + ((gg & 511) >> 3)],
               nib << ((gg & 7) << 2));
    }
    int4 av1[4];
#pragma unroll
    for (int u = 0; u < 4; ++u) av1[u] = adj4[(t << 11) + ((u + 4) << 8) + tid];
    __syncthreads();  // S3: gbuf ready
    float gi = gbuf[w][lane];
    float gf = gbuf[w][64 + lane];
    float gg0 = gbuf[w][128 + lane];
    float go = gbuf[w][192 + lane];
    c = sigf(gf) * c + sigf(gi) * tanhfast(gg0);
    float h = sigf(go) * tanhfast(c);
    xh[w][32 + lane] = h;  // all GEMM(t) reads done at S3 -> safe WAR

    // gatprep: wave-local (own wave's h region; lgkmcnt-ordered)
    float wh = 0.f;
    const float4* hq = (const float4*)&xh[w][32];
#pragma unroll
    for (int kq = 0; kq < 16; ++kq) {
      float4 hvv = hq[kq];
      wh += hvv.x * wgreg[(kq << 2) + 0] + hvv.y * wgreg[(kq << 2) + 1] +
            hvv.z * wgreg[(kq << 2) + 2] + hvv.w * wgreg[(kq << 2) + 3];
    }
    float s = wh * as, d = wh * ad;
#pragma unroll
    for (int off = 32; off > 0; off >>= 1) {
      s += __shfl_xor(s, off, 64);
      d += __shfl_xor(d, off, 64);
    }
    if (lane == 0) {
      sv[t * NN + node_w] = s;
      dv[t * NN + node_w] = d;
    }
    WhFr[((size_t)t * 16384 + o8base) * 8 + jj] = __float2bfloat16(wh);

    // write staged hist(t+1)
    if (t < 7 && tid < 160) xstage[(t + 1) & 1][snd][sr] = hv;
    // consume batch B
#pragma unroll
    for (int u = 0; u < 4; ++u) {
      int gg2 = (t << 11) + ((u + 4) << 8) + tid;
      unsigned nib = (av1[u].x != 0 ? 1u : 0u) | (av1[u].y != 0 ? 2u : 0u) |
                     (av1[u].z != 0 ? 4u : 0u) | (av1[u].w != 0 ? 8u : 0u);
      atomicOr(&pmsk[((gg2 >> 9) << 6) + ((gg2 & 511) >> 3)],
               nib << ((gg2 & 7) << 2));
    }
    __syncthreads();  // S4
  }
  // dump packed masks
  const int4* ps = (const int4*)pmsk;
  int4* gm4 = (int4*)gmask + ((size_t)blockIdx.x << 9);
  gm4[tid] = ps[tid];
  gm4[256 + tid] = ps[256 + tid];
}

// ---------------------------------------------------------------- GAT
// 32-row i-tile per block (512 blocks, 2/CU exact residency): each block
// computes TWO 16-row tiles sharing one b-fragment stream -> WhFr L2 traffic
// halves (256->128 MB), dv/gmask reloads halve. Occupancy drop (2 waves/SIMD)
// compensated by a 1-deep b-frag prefetch in the ks loop. Reduction reuses
// abuf in two passes; per-output summation order identical to the verified
// 16-row version (same wave->ks split, same ww order) -> bit-identical.
__global__ __launch_bounds__(256, 2) void k_gat(
    const unsigned* __restrict__ gmask, const __hip_bfloat16* __restrict__ WhFr,
    const float* __restrict__ sv, const float* __restrict__ dv,
    void* __restrict__ out, cvp W_ih) {
  __shared__ __align__(16) float dv_s[NN];      // 8 KB
  __shared__ unsigned int msk[32 * 65];         // 8.3 KB, bank-padded
  __shared__ floatx4 abuf[3][5][64];            // 15 KB (two-pass reuse)
  int bf = detect_bf(W_ih);
  int tid = threadIdx.x;
  int w = tid >> 6, lane = tid & 63;
  int b = blockIdx.x >> 6;
  int i0 = (blockIdx.x & 63) << 5;
  int q = lane >> 4, m = lane & 15;

  // masks: rows b*NN+i0 .. +31 = 512 int4, two per thread
  const int4* gm4 = (const int4*)gmask + (((size_t)b * NN + i0) << 4);
#pragma unroll
  for (int u = 0; u < 2; ++u) {
    int idx = (u << 8) + tid;
    int4 mv = gm4[idx];
    int mrow = idx >> 4, mwd = (idx & 15) << 2;
    unsigned* mp = &msk[mrow * 65 + mwd];
    mp[0] = (unsigned)mv.x; mp[1] = (unsigned)mv.y;
    mp[2] = (unsigned)mv.z; mp[3] = (unsigned)mv.w;
  }
  {
    const float4* dsrc = (const float4*)(dv + (size_t)b * NN);
    ((float4*)dv_s)[tid] = dsrc[tid];
    ((float4*)dv_s)[256 + tid] = dsrc[256 + tid];
  }
  float sva0 = sv[b * NN + i0 + m];
  float sva1 = sv[b * NN + i0 + 16 + m];
  __syncthreads();

  short8 ones;
#pragma unroll
  for (int p = 0; p < 8; ++p) ones[p] = (short)0x3F80;

  const short8* base = ((const short8*)WhFr) + (size_t)b * 16384 + lane;
  int ksb = w << 4, kse = ksb + 16;
  floatx4 z = {0.f, 0.f, 0.f, 0.f};
  floatx4 a0a = z, a1a = z, a2a = z, a3a = z, aSa = z;
  floatx4 a0b = z, a1b = z, a2b = z, a3b = z, aSb = z;

  // prefetch first b-frags
  const short8* bp = base + (size_t)ksb * 256;
  short8 nb0 = bp[0], nb1 = bp[64], nb2 = bp[128], nb3 = bp[192];

  for (int ks = ksb; ks < kse; ++ks) {
    short8 b0 = nb0, b1 = nb1, b2 = nb2, b3 = nb3;
    if (ks + 1 < kse) {
      const short8* np = base + (size_t)(ks + 1) * 256;
      nb0 = np[0]; nb1 = np[64]; nb2 = np[128]; nb3 = np[192];
    }
    unsigned mw0 = msk[m * 65 + ks];
    unsigned mw1 = msk[(16 + m) * 65 + ks];
    float4 d0 = *(const float4*)&dv_s[(ks << 5) + (q << 3)];
    float4 d1 = *(const float4*)&dv_s[(ks << 5) + (q << 3) + 4];
    float dd[8] = {d0.x, d0.y, d0.z, d0.w, d1.x, d1.y, d1.z, d1.w};
    float pv0[8], pv1[8];
#pragma unroll
    for (int jj = 0; jj < 8; ++jj) {
      float t0 = sva0 + dd[jj];
      float e0 = __expf(fmaxf(t0, 0.2f * t0));
      pv0[jj] = ((mw0 >> ((q << 3) + jj)) & 1u) ? e0 : 0.f;
      float t1 = sva1 + dd[jj];
      float e1 = __expf(fmaxf(t1, 0.2f * t1));
      pv1[jj] = ((mw1 >> ((q << 3) + jj)) & 1u) ? e1 : 0.f;
    }
    short8 afr0, afr1;
#pragma unroll
    for (int p2 = 0; p2 < 4; ++p2) {
      ((__hip_bfloat162*)&afr0)[p2] =
          __float22bfloat162_rn(make_float2(pv0[2 * p2], pv0[2 * p2 + 1]));
      ((__hip_bfloat162*)&afr1)[p2] =
          __float22bfloat162_rn(make_float2(pv1[2 * p2], pv1[2 * p2 + 1]));
    }
    a0a = __builtin_amdgcn_mfma_f32_16x16x32_bf16(afr0, b0, a0a, 0, 0, 0);
    a1a = __builtin_amdgcn_mfma_f32_16x16x32_bf16(afr0, b1, a1a, 0, 0, 0);
    a2a = __builtin_amdgcn_mfma_f32_16x16x32_bf16(afr0, b2, a2a, 0, 0, 0);
    a3a = __builtin_amdgcn_mfma_f32_16x16x32_bf16(afr0, b3, a3a, 0, 0, 0);
    aSa = __builtin_amdgcn_mfma_f32_16x16x32_bf16(afr0, ones, aSa, 0, 0, 0);
    a0b = __builtin_amdgcn_mfma_f32_16x16x32_bf16(afr1, b0, a0b, 0, 0, 0);
    a1b = __builtin_amdgcn_mfma_f32_16x16x32_bf16(afr1, b1, a1b, 0, 0, 0);
    a2b = __builtin_amdgcn_mfma_f32_16x16x32_bf16(afr1, b2, a2b, 0, 0, 0);
    a3b = __builtin_amdgcn_mfma_f32_16x16x32_bf16(afr1, b3, a3b, 0, 0, 0);
    aSb = __builtin_amdgcn_mfma_f32_16x16x32_bf16(afr1, ones, aSb, 0, 0, 0);
  }

  // ---- two-pass cross-wave reduction + epilogue (abuf reused)
#pragma unroll
  for (int tile = 0; tile < 2; ++tile) {
    floatx4 c0 = tile ? a0b : a0a;
    floatx4 c1 = tile ? a1b : a1a;
    floatx4 c2 = tile ? a2b : a2a;
    floatx4 c3 = tile ? a3b : a3a;
    floatx4 cS = tile ? aSb : aSa;
    if (w > 0) {
      abuf[w - 1][0][lane] = c0;
      abuf[w - 1][1][lane] = c1;
      abuf[w - 1][2][lane] = c2;
      abuf[w - 1][3][lane] = c3;
      abuf[w - 1][4][lane] = cS;
    }
    __syncthreads();
    if (w == 0) {
#pragma unroll
      for (int ww = 0; ww < 3; ++ww) {
        c0 += abuf[ww][0][lane];
        c1 += abuf[ww][1][lane];
        c2 += abuf[ww][2][lane];
        c3 += abuf[ww][3][lane];
        cS += abuf[ww][4][lane];
      }
      floatx4 accs[4] = {c0, c1, c2, c3};
      float inv[4];
#pragma unroll
      for (int r = 0; r < 4; ++r) inv[r] = 1.f / cS[r];
      int rbase = i0 + (tile << 4) + (q << 2);
      if (bf) {
        __hip_bfloat16* o = (__hip_bfloat16*)out;
#pragma unroll
        for (int nt = 0; nt < 4; ++nt)
#pragma unroll
          for (int r = 0; r < 4; ++r) {
            float v = accs[nt][r] * inv[r];
            v = (v > 0.f) ? v : expm1f(v);
            o[((size_t)b * NN + rbase + r) * H2 + (nt << 4) + m] =
                __float2bfloat16(v);
          }
      } else {
        float* o = (float*)out;
#pragma unroll
        for (int nt = 0; nt < 4; ++nt)
#pragma unroll
          for (int r = 0; r < 4; ++r) {
            float v = accs[nt][r] * inv[r];
            v = (v > 0.f) ? v : expm1f(v);
            o[((size_t)b * NN + rbase + r) * H2 + (nt << 4) + m] = v;
          }
      }
    }
    __syncthreads();  // w0 done reading abuf before tile-1 overwrite
  }
}

// ---------------------------------------------------------------- launch
extern "C" void kernel_launch(void* const* d_in, const int* in_sizes, int n_in,
                              void* d_out, int out_size, void* d_ws, size_t ws_size,
                              hipStream_t stream) {
  (void)in_sizes; (void)n_in; (void)out_size; (void)ws_size;
  cvp hist  = d_in[0];
  const int* adj = (const int*)d_in[1];
  cvp W1    = d_in[2];
  cvp b1    = d_in[3];
  cvp W_ih  = d_in[4];
  cvp W_hh  = d_in[5];
  cvp b_ih  = d_in[6];
  cvp b_hh  = d_in[7];
  cvp Wg    = d_in[8];
  cvp a_src = d_in[9];
  cvp a_dst = d_in[10];

  float* ws = (float*)d_ws;
  __hip_bfloat16* WhFr = (__hip_bfloat16*)d_ws;        // 2 MB
  float* sv = ws + 524288;                             // B*N floats
  float* dv = sv + BB * NN;                            // B*N floats
  unsigned* gmask = (unsigned*)(dv + BB * NN);         // 4 MB packed masks

  k_lstm<<<512, 256, 0, stream>>>(hist, W1, b1, W_ih, W_hh, b_ih, b_hh,
                                  Wg, a_src, a_dst, adj, WhFr, sv, dv, gmask);
  k_gat<<<512, 256, 0, stream>>>(gmask, WhFr, sv, dv, d_out, W_ih);
}